// Round 3
// baseline (472.626 us; speedup 1.0000x reference)
//
#include <hip/hip_runtime.h>

// ParallelTransport: out[e,c,:] = R(rho[e]) @ x[row[e], c, :]
// R = [[c,-s],[s,c]]; layout (...,C,2): consecutive f32 are (comp0,comp1).
// Dtypes (verified R2): x f32, edge_index int32 (harness-converted), rho f32,
// out f32 (reference output dtype; R2's bf16-out read-back-as-f32 was the bug).
//
// 8 threads/edge: each loads 8 f32 (2x float4, 32B) = 4 channel-pairs,
// rotates, stores 8 f32. Wave64 = 8 edges: 2KiB contiguous load (x row,
// L2-resident) + 2KiB contiguous store.

__device__ __forceinline__ float2 rot_pair(float p0, float p1, float c, float s) {
    float2 y;
    y.x = fmaf(c, p0, -(s * p1));   // c*p0 - s*p1
    y.y = fmaf(s, p0,  c * p1);     // s*p0 + c*p1
    return y;
}

__global__ __launch_bounds__(256) void ParallelTransport_kernel(
    const float* __restrict__ x,      // (N, 32, 2) = N*64 f32
    const int*   __restrict__ row,    // edge_index[0], E int32
    const float* __restrict__ rho,    // E f32
    float*       __restrict__ out,    // (E, 32, 2) = E*64 f32
    int E)
{
    int t = blockIdx.x * blockDim.x + threadIdx.x;
    int e = t >> 3;          // edge
    int k = t & 7;           // 32B chunk within the edge's 256B row
    if (e >= E) return;

    int   r   = row[e];
    float ang = rho[e];
    float s, c;
    __sincosf(ang, &s, &c);

    const float4* src = reinterpret_cast<const float4*>(
        x + ((size_t)r << 6) + (k << 3));
    float4 a = src[0];
    float4 b = src[1];

    float2 p0 = rot_pair(a.x, a.y, c, s);
    float2 p1 = rot_pair(a.z, a.w, c, s);
    float2 p2 = rot_pair(b.x, b.y, c, s);
    float2 p3 = rot_pair(b.z, b.w, c, s);

    float4* dst = reinterpret_cast<float4*>(
        out + ((size_t)e << 6) + (k << 3));
    dst[0] = make_float4(p0.x, p0.y, p1.x, p1.y);
    dst[1] = make_float4(p2.x, p2.y, p3.x, p3.y);
}

extern "C" void kernel_launch(void* const* d_in, const int* in_sizes, int n_in,
                              void* d_out, int out_size, void* d_ws, size_t ws_size,
                              hipStream_t stream) {
    const float* x   = (const float*)d_in[0];
    const int*   ei  = (const int*)d_in[1];    // (2,E) int32; row = first E
    const float* rho = (const float*)d_in[2];
    float*       out = (float*)d_out;

    const int E = in_sizes[2];                 // rho element count
    const int threads = E * 8;
    const int block = 256;
    const int grid = (threads + block - 1) / block;

    ParallelTransport_kernel<<<grid, block, 0, stream>>>(x, ei, rho, out, E);
}